// Round 7
// baseline (2863.212 us; speedup 1.0000x reference)
//
#include <hip/hip_runtime.h>
#include <hip/hip_bf16.h>
#include <math.h>

// Problem constants
#define BB 64
#define TT 512
#define II 256
#define HH 512
#define GG 2048   // 4H

typedef unsigned char u8;
typedef unsigned short u16;
typedef unsigned int u32;
typedef __attribute__((ext_vector_type(4))) int   i32x4;
typedef __attribute__((ext_vector_type(2))) int   i32x2;
typedef __attribute__((ext_vector_type(8))) short short8v;
typedef __attribute__((ext_vector_type(4))) float f32x4;

__device__ __forceinline__ u16 f2bf(float f) {
    unsigned u = __float_as_uint(f);
    unsigned r = (u + 0x7fff + ((u >> 16) & 1)) >> 16;  // RNE
    return (u16)r;
}
__device__ __forceinline__ float bf2f(u16 h) {
    return __uint_as_float(((unsigned)h) << 16);
}
__device__ __forceinline__ float sigf(float v) {
    return 1.f / (1.f + __expf(-v));
}
__device__ __forceinline__ float tanh_s(float v) {
    float a = fabsf(v);
    float e = __expf(2.f * a);
    float r = 1.f - 2.f / (e + 1.f);
    return copysignf(r, v);
}

// 16B MALL-coherent load (bypass L1/L2)
#define HLD(dst, ptr) \
    asm volatile("global_load_dwordx4 %0, %1, off sc0 sc1" : "=v"(dst) : "v"(ptr))
// 16B x load: saddr + 32-bit voffset (plain caching)
#define XLD(dst, voff, sbase) \
    asm volatile("global_load_dwordx4 %0, %1, %2" : "=v"(dst) : "v"(voff), "s"(sbase))
// packed f32x2 -> bf16x2 (RNE, HW)
#define CVTPK(d, lo, hi) \
    asm("v_cvt_pk_bf16_f32 %0, %1, %2" : "=v"(d) : "v"(lo), "v"(hi))

__global__ void __launch_bounds__(256, 1) slstm_kernel(
    const float* __restrict__ x, const float* __restrict__ wih,
    const float* __restrict__ whh, const float* __restrict__ bias,
    float* __restrict__ out, u8* __restrict__ flagb,
    u16* __restrict__ hbuf /* [2 parity][2 hi/lo][BB][HH] bf16 */)
{
    __shared__ __attribute__((aligned(16))) u16 lds_wih[128 * 256]; // q=2,3 XOR-swz 64KB
    __shared__ __attribute__((aligned(16))) u16 lds_h[2 * 16 * 512]; // hi/lo XOR-swz 32KB
    __shared__ __attribute__((aligned(16))) u16 lds_x[16 * 264];     // pad-264     8.25KB

    const int tid = threadIdx.x;
    const int l  = tid & 63, w = tid >> 6;   // lane, wave
    const int bt = blockIdx.x & 3;           // chain (b-tile)
    const int pj = blockIdx.x >> 2;          // producer block 0..7
    const int b0 = bt * 16;
    const int j0 = pj * 64 + w * 16;         // wave's 16 h-cols
    const int c  = l & 15, kq = l >> 4;

    // ---- W_hh B-frags -> VGPR (256 regs/wave, resident all run) ----
    short8v wb[4][16];
#pragma unroll
    for (int q = 0; q < 4; ++q) {
        const float* wc = whh + (q * 512 + j0 + c);
#pragma unroll
        for (int s = 0; s < 16; ++s) {
            short8v v;
#pragma unroll
            for (int jj = 0; jj < 8; ++jj)
                v[jj] = (short)f2bf(wc[(size_t)(32 * s + 8 * kq + jj) * GG]);
            wb[q][s] = v;
        }
    }
    // ---- W_ih q=0,1 B-frags -> VGPR (64 regs) ----
    short8v wibr[2][8];
#pragma unroll
    for (int q = 0; q < 2; ++q) {
        const float* wc = wih + (q * 512 + j0 + c);
#pragma unroll
        for (int s = 0; s < 8; ++s) {
            short8v v;
#pragma unroll
            for (int jj = 0; jj < 8; ++jj)
                v[jj] = (short)f2bf(wc[(size_t)(32 * s + 8 * kq + jj) * GG]);
            wibr[q][s] = v;
        }
    }
    // ---- W_ih q=2,3 -> LDS, [rr][k] bf16, XOR swizzle ----
    {
        int rr = tid >> 1, kh = (tid & 1) * 128;
        int col = (2 + (rr >> 6)) * 512 + pj * 64 + (rr & 63);
        for (int kk = 0; kk < 128; ++kk) {
            int k = kh + kk;
            u32 off = ((u32)(rr * 512 + k * 2)) ^ (u32)((rr & 7) << 4);
            *(u16*)((char*)lds_wih + off) = f2bf(wih[(size_t)k * GG + col]);
        }
    }

    float bq[4];
#pragma unroll
    for (int q = 0; q < 4; ++q) bq[q] = bias[q * 512 + j0 + c];
    float cst[4] = {0.f, 0.f, 0.f, 0.f};

    // ---- x(0) -> regs -> lds_x ----
    f32x4 xs[4];
#pragma unroll
    for (int i = 0; i < 4; ++i) {
        int ch = i * 256 + tid;
        u32 vo = (u32)(((b0 + (ch >> 6)) * TT + 0) * II * 4 + (ch & 63) * 16);
        XLD(xs[i], vo, x);
    }
    asm volatile("s_waitcnt vmcnt(0)" ::: "memory");
    __builtin_amdgcn_sched_barrier(0);
#pragma unroll
    for (int i = 0; i < 4; ++i) {
        int ch = i * 256 + tid;
        i32x2 p;
        CVTPK(p[0], xs[i][0], xs[i][1]);
        CVTPK(p[1], xs[i][2], xs[i][3]);
        *(i32x2*)((char*)lds_x + (u32)((ch >> 6) * 528 + (ch & 63) * 8)) = p;
    }
    __syncthreads();

    f32x4 acc[4];
#define LDW23(Q, S) (*(const short8v*)((const char*)lds_wih + \
        ((((u32)(((Q) - 2) * 64 + w * 16 + c)) * 512 + 64 * (S) + 16 * kq) ^ \
         (u32)((((((Q) - 2) * 64 + w * 16 + c)) & 7) << 4))))
#define XPGEMM() do { \
    _Pragma("unroll") for (int q = 0; q < 4; ++q) \
        acc[q] = (f32x4){bq[q], bq[q], bq[q], bq[q]}; \
    _Pragma("unroll") for (int s = 0; s < 8; ++s) { \
        short8v a_ = *(const short8v*)((const char*)lds_x + (u32)(c * 528 + 64 * s + 16 * kq)); \
        acc[0] = __builtin_amdgcn_mfma_f32_16x16x32_bf16(a_, wibr[0][s], acc[0], 0, 0, 0); \
        acc[1] = __builtin_amdgcn_mfma_f32_16x16x32_bf16(a_, wibr[1][s], acc[1], 0, 0, 0); \
        acc[2] = __builtin_amdgcn_mfma_f32_16x16x32_bf16(a_, LDW23(2, s), acc[2], 0, 0, 0); \
        acc[3] = __builtin_amdgcn_mfma_f32_16x16x32_bf16(a_, LDW23(3, s), acc[3], 0, 0, 0); \
    } } while (0)

    XPGEMM();   // acc = xp(0)

#define LDH(S, PL) (*(const short8v*)((const char*)lds_h + \
        ((PL) * 16384 + (((u32)c * 1024 + 64 * (S) + 16 * kq) ^ (u32)((c & 7) << 4)))))

    for (int t = 0; t < TT; ++t) {
        const int have = (t > 0);
        i32x4 hst[8];

        if (have) {
            // ---- poll the 8 producer flags of step t-1 (single 8B line) ----
            const u8* fb = flagb + ((size_t)(bt * TT + (t - 1))) * 8;
            while (true) {
                i32x2 fw;
                asm volatile("global_load_dwordx2 %0, %1, off sc0 sc1\n\t"
                             "s_waitcnt vmcnt(0)"
                             : "=v"(fw) : "v"(fb) : "memory");
                if ((fw[0] & fw[1]) == 0x01010101) break;
                __builtin_amdgcn_s_sleep(1);
            }
            __builtin_amdgcn_sched_barrier(0);
            // ---- cooperative h_{t-1} load: 32KB (hi+lo) / 256 threads ----
            const u16* hbase = hbuf + (size_t)(((t - 1) & 1) * 2) * BB * HH;
#pragma unroll
            for (int i = 0; i < 8; ++i) {
                int ch = i * 256 + tid;               // 2048 chunks of 16B
                const u16* src = hbase + (size_t)(ch >> 10) * BB * HH
                                 + (size_t)(b0 + ((ch & 1023) >> 6)) * HH
                                 + (ch & 63) * 8;
                HLD(hst[i], src);
            }
        }

        // ---- x(t+1) prefetch (issued after h: h are the oldest in vmcnt) ----
        const int tn = (t + 1 < TT) ? (t + 1) : (TT - 1);
#pragma unroll
        for (int i = 0; i < 4; ++i) {
            int ch = i * 256 + tid;
            u32 vo = (u32)(((b0 + (ch >> 6)) * TT + tn) * II * 4 + (ch & 63) * 16);
            XLD(xs[i], vo, x);
        }

        if (have) {
            asm volatile("s_waitcnt vmcnt(4)" ::: "memory");   // 8 h done, 4 x in flight
            __builtin_amdgcn_sched_barrier(0);
#pragma unroll
            for (int i = 0; i < 8; ++i) {
                int ch = i * 256 + tid;
                int pl = ch >> 10, cc = ch & 1023, r = cc >> 6;
                u32 off = (u32)pl * 16384 +
                          (((u32)r * 1024 + (u32)(cc & 63) * 16) ^ (u32)((r & 7) << 4));
                *(i32x4*)((char*)lds_h + off) = hst[i];
            }
        }
        __syncthreads();   // h tile visible to all 4 waves (drains x too)

        if (have) {
            // ---- gates += (h_hi + h_lo) @ W_hh : B-frags from VGPR ----
#pragma unroll
            for (int s = 0; s < 16; ++s) {
                short8v ah = LDH(s, 0);
                short8v al = LDH(s, 1);
#pragma unroll
                for (int q = 0; q < 4; ++q)
                    acc[q] = __builtin_amdgcn_mfma_f32_16x16x32_bf16(ah, wb[q][s], acc[q], 0, 0, 0);
#pragma unroll
                for (int q = 0; q < 4; ++q)
                    acc[q] = __builtin_amdgcn_mfma_f32_16x16x32_bf16(al, wb[q][s], acc[q], 0, 0, 0);
            }
        }

        // ---- epilogue: activations, c update, hbuf hi/lo stores ----
        const int wp = t & 1;
        u16* hdst_hi = hbuf + (size_t)(wp * 2) * BB * HH;
        u16* hdst_lo = hdst_hi + BB * HH;
        const int j = j0 + c;
        float hyv[4];
#pragma unroll
        for (int rg = 0; rg < 4; ++rg) {
            int b = b0 + kq * 4 + rg;
            float ig = sigf(acc[0][rg]);
            float fg = sigf(acc[1][rg]);
            float cg = tanh_s(acc[2][rg]);
            float og = acc[3][rg];            // reference: NO sigmoid on outgate
            float cy = fg * cst[rg] + ig * cg;
            cst[rg] = cy;
            float hy = og * tanh_s(cy) + og;  // hy = og*tanh(cy) + og (reference quirk)
            hyv[rg] = hy;
            u16 hi = f2bf(hy);
            float lo = hy - bf2f(hi);
            __hip_atomic_store(&hdst_hi[(size_t)b * HH + j], hi,
                               __ATOMIC_RELAXED, __HIP_MEMORY_SCOPE_AGENT);
            __hip_atomic_store(&hdst_lo[(size_t)b * HH + j], f2bf(lo),
                               __ATOMIC_RELAXED, __HIP_MEMORY_SCOPE_AGENT);
        }

        // ---- drain all waves' hbuf stores, then ONE flag byte per block ----
        asm volatile("s_waitcnt vmcnt(0)" ::: "memory");
        __syncthreads();
        if (tid == 0) {
            u8* fa = flagb + ((size_t)(bt * TT + t)) * 8 + pj;
            __hip_atomic_store(fa, (u8)1, __ATOMIC_RELAXED, __HIP_MEMORY_SCOPE_AGENT);
        }

        // ---- x(t+1) regs -> lds_x (loads retired by the drain above) ----
        __builtin_amdgcn_sched_barrier(0);
#pragma unroll
        for (int i = 0; i < 4; ++i) {
            int ch = i * 256 + tid;
            i32x2 p;
            CVTPK(p[0], xs[i][0], xs[i][1]);
            CVTPK(p[1], xs[i][2], xs[i][3]);
            *(i32x2*)((char*)lds_x + (u32)((ch >> 6) * 528 + (ch & 63) * 8)) = p;
        }
        __syncthreads();   // lds_x ready for all waves

        // ---- out stores (drain under next step's poll) ----
#pragma unroll
        for (int rg = 0; rg < 4; ++rg) {
            int b = b0 + kq * 4 + rg;
            out[((size_t)b * TT + t) * HH + j] = hyv[rg];
        }

        // ---- xp(t+1) -> acc (off the inter-block critical path) ----
        XPGEMM();
    }
}

extern "C" void kernel_launch(void* const* d_in, const int* in_sizes, int n_in,
                              void* d_out, int out_size, void* d_ws, size_t ws_size,
                              hipStream_t stream) {
    const float* x    = (const float*)d_in[0];
    const float* wih  = (const float*)d_in[1];
    const float* whh  = (const float*)d_in[2];
    const float* bias = (const float*)d_in[3];
    float* out = (float*)d_out;

    // ws: [0,16KB) byte flags [4 chains][512 t][8 producers]; [16KB,+512KB) h ping-pong
    u8*  flagb = (u8*)d_ws;
    u16* hbuf  = (u16*)((char*)d_ws + 16384);
    hipMemsetAsync(d_ws, 0, 16384, stream);   // flags=0 each launch (t=0 reads no h)

    hipLaunchKernelGGL(slstm_kernel, dim3(32), dim3(256), 0, stream,
                       x, wih, whh, bias, out, flagb, hbuf);
}